// Round 1
// baseline (427.683 us; speedup 1.0000x reference)
//
#include <hip/hip_runtime.h>

// CVMerge inference: out[n, :] = x_{fold[n]}[n/4, :]  (fold = arange(N) % 4,
// so rows of fold-value i are i, i+4, i+8, ... and the j-th such row gets
// x_i[j]). Pure 4-way row-interleave copy; memory-bound.
//
// One thread per float4 (16 B/lane). Writes fully contiguous; reads are
// 128 B contiguous segments per source row (8 lanes). fold[n] read is
// broadcast across the row's 8 lanes (same address -> one transaction).

__global__ __launch_bounds__(256) void CVMerge_41472204210311_kernel(
    const float4* __restrict__ x0,
    const float4* __restrict__ x1,
    const float4* __restrict__ x2,
    const float4* __restrict__ x3,
    const int*    __restrict__ fold,
    float4*       __restrict__ out,
    unsigned n_vec4)                     // N * (D/4) = 16,777,216
{
    unsigned g = blockIdx.x * 256u + threadIdx.x;  // float4 index
    if (g >= n_vec4) return;

    unsigned n  = g >> 3;   // output row (D=32 -> 8 float4 per row)
    unsigned d4 = g & 7u;   // float4 within row
    unsigned j  = n >> 2;   // row within the source fold buffer

    int i = fold[n];
    const float4* __restrict__ p = (i == 0) ? x0
                                 : (i == 1) ? x1
                                 : (i == 2) ? x2
                                 :            x3;
    out[g] = p[j * 8u + d4];
}

extern "C" void kernel_launch(void* const* d_in, const int* in_sizes, int n_in,
                              void* d_out, int out_size, void* d_ws, size_t ws_size,
                              hipStream_t stream) {
    const float4* x0  = (const float4*)d_in[0];
    const float4* x1  = (const float4*)d_in[1];
    const float4* x2  = (const float4*)d_in[2];
    const float4* x3  = (const float4*)d_in[3];
    const int*   fold = (const int*)d_in[4];
    float4* out = (float4*)d_out;

    // out_size = N * D elements; D = 32 -> n_vec4 = out_size / 4
    unsigned n_vec4 = (unsigned)(out_size / 4);
    unsigned grid = (n_vec4 + 255u) / 256u;

    CVMerge_41472204210311_kernel<<<grid, 256, 0, stream>>>(
        x0, x1, x2, x3, fold, out, n_vec4);
}